// Round 7
// baseline (244.034 us; speedup 1.0000x reference)
//
#include <hip/hip_runtime.h>
#include <hip/hip_bf16.h>

#define HW 1024
#define C_CH 768
#define BATCH 16
#define NG 32
#define CPG 24
#define EPS 1e-5f

typedef __attribute__((ext_vector_type(8))) short bf16x8;
typedef __attribute__((ext_vector_type(4))) float f32x4;
typedef unsigned short u16;
typedef unsigned int u32;

typedef const __attribute__((address_space(1))) void* gas_ptr;
typedef __attribute__((address_space(3))) void* las_ptr;

__device__ __forceinline__ void load_lds16(const void* g, void* l) {
    __builtin_amdgcn_global_load_lds((gas_ptr)g, (las_ptr)l, 16, 0, 0);
}

__device__ __forceinline__ u16 f2bf(float f) {
    __hip_bfloat16 h = __float2bfloat16(f);
    return *(u16*)&h;
}
__device__ __forceinline__ float bf2f(u16 u) {
    return __uint_as_float(((u32)u) << 16);
}

// Bijective XCD-chunked swizzle (m204): consecutive blockIdx round-robin across the 8
// XCD L2s; remap so each XCD gets a CONTIGUOUS chunk of the grid (~2 whole batches ->
// q/k/att panels become L2-resident per XCD instead of 16-batch thrash).
__device__ __forceinline__ int xcd_remap(int& bx, int& by, int& bz) {
    const int nbx = gridDim.x, nby = gridDim.y;
    const int nwg = nbx * nby * gridDim.z;
    int bid = blockIdx.x + nbx * (blockIdx.y + nby * blockIdx.z);
    const int orig = bid;
    if ((nwg & 7) == 0) {
        const int q = nwg >> 3;
        bid = (bid & 7) * q + (bid >> 3);
    }
    bx = bid % nbx;
    int t2 = bid / nbx;
    by = t2 % nby;
    bz = t2 / nby;
    return orig;
}

// ---------------- cast f32 -> bf16 (vectorized x4) ----------------
__global__ __launch_bounds__(256) void cast_bf16_kernel(const float4* __restrict__ in,
                                                        ushort4* __restrict__ out, int n4) {
    int i = blockIdx.x * 256 + threadIdx.x;
    if (i >= n4) return;
    float4 v = in[i];
    ushort4 u;
    u.x = f2bf(v.x); u.y = f2bf(v.y); u.z = f2bf(v.z); u.w = f2bf(v.w);
    out[i] = u;
}

// ---------------- GroupNorm stats: one block per (b,g) ----------------
__global__ __launch_bounds__(256) void gn_stats_kernel(const float* __restrict__ x,
                                                       float* __restrict__ stats) {
    int bg = blockIdx.x;                       // b*NG + g
    const float4* p4 = (const float4*)(x + (size_t)bg * (CPG * HW));
    float s = 0.f, s2 = 0.f;
    for (int i = threadIdx.x; i < (CPG * HW) / 4; i += 256) {
        float4 v = p4[i];
        s  += v.x + v.y + v.z + v.w;
        s2 += v.x * v.x + v.y * v.y + v.z * v.z + v.w * v.w;
    }
    int lane = threadIdx.x & 63, wid = threadIdx.x >> 6;
    for (int off = 32; off; off >>= 1) {
        s  += __shfl_xor(s,  off, 64);
        s2 += __shfl_xor(s2, off, 64);
    }
    __shared__ float red[8];
    if (lane == 0) { red[wid * 2] = s; red[wid * 2 + 1] = s2; }
    __syncthreads();
    if (threadIdx.x == 0) {
        s = red[0] + red[2] + red[4] + red[6];
        s2 = red[1] + red[3] + red[5] + red[7];
        float mean = s / (float)(CPG * HW);
        float var  = s2 / (float)(CPG * HW) - mean * mean;
        stats[2 * bg]     = mean;
        stats[2 * bg + 1] = rsqrtf(var + EPS);
    }
}

// ------------- GroupNorm normalize + transpose -> xn_T [B, HW, C] bf16 -------------
__global__ __launch_bounds__(256) void gn_norm_kernel(const float* __restrict__ x,
                                                      const float* __restrict__ stats,
                                                      const float* __restrict__ gamma,
                                                      const float* __restrict__ beta,
                                                      __hip_bfloat16* __restrict__ xnT) {
    __shared__ float lds[64][65];
    int b  = blockIdx.y;
    int p0 = blockIdx.x * 64;
    int t = threadIdx.x;
    int lane = t & 63;
    int grp  = t >> 6;   // 0..3
    for (int cc = 0; cc < C_CH / 64; cc++) {
        int c0 = cc * 64;
        for (int i = 0; i < 16; i++) {
            int c = c0 + grp * 16 + i;
            float2 st = ((const float2*)stats)[b * NG + c / CPG];
            float ga = gamma[c], be = beta[c];
            float v = x[((size_t)b * C_CH + c) * HW + p0 + lane];
            lds[lane][grp * 16 + i] = (v - st.x) * st.y * ga + be;
        }
        __syncthreads();
        for (int i = 0; i < 16; i++) {
            int pp = grp * 16 + i;
            xnT[((size_t)b * HW + p0 + pp) * C_CH + c0 + lane] =
                __float2bfloat16(lds[pp][lane]);
        }
        __syncthreads();
    }
}

// ---------------- row softmax over att [rows][768] bf16, in place ----------------
__global__ __launch_bounds__(256) void softmax_kernel(__hip_bfloat16* __restrict__ att) {
    int row  = blockIdx.x * 4 + (threadIdx.x >> 6);
    int lane = threadIdx.x & 63;
    u16* p = (u16*)(att + (size_t)row * C_CH);
    float v[12];
    float m = -1e30f;
    for (int j = 0; j < 12; j++) {
        v[j] = bf2f(p[j * 64 + lane]);
        m = fmaxf(m, v[j]);
    }
    for (int off = 32; off; off >>= 1) m = fmaxf(m, __shfl_xor(m, off, 64));
    float s = 0.f;
    for (int j = 0; j < 12; j++) { v[j] = __expf(v[j] - m); s += v[j]; }
    for (int off = 32; off; off >>= 1) s += __shfl_xor(s, off, 64);
    float inv = 1.0f / s;
    for (int j = 0; j < 12; j++) p[j * 64 + lane] = f2bf(v[j] * inv);
}

// ---------------- NT GEMM: C[m,n] = scale * sum_k A[m,k]*B[n,k] (+bias/res) ----------------
// A: [M x K] row-major (rows at stride K), B: [N x K] row-major.
// Tile 128x128, BK=64, 4 waves each owning 64x64. global_load_lds staging with
// XOR-swizzled source so ds_read_b128 frag reads are conflict-free (verified: 0 conflicts).
// NEW (R7): per-block K-loop PHASE ROTATION. All blocks previously staged/drained/computed
// in lockstep (convoy) -> vmcnt(0) drains never overlapped with other blocks' MFMA.
// Block starts its K-loop at step (origBid % nk) and wraps; fp32 accumulation is
// order-independent up to rounding. Neighboring blocks (same CU) get different phases.
template<int OUT_F32>
__global__ __launch_bounds__(256, 2) void gemm_nt_kernel(
    const __hip_bfloat16* __restrict__ A, long sA,
    const __hip_bfloat16* __restrict__ B, long sB,
    void* __restrict__ Cout, long sC, int ldc,
    int K, float scale,
    const float* __restrict__ bias_row,
    const float* __restrict__ bias_col,
    const float* __restrict__ residual, long sR,
    __hip_bfloat16* __restrict__ vt_out, long sVT, int vt_start)
{
    __shared__ __hip_bfloat16 ldsA[128 * 64];
    __shared__ __hip_bfloat16 ldsB[128 * 64];
    int bxx, byy, bzz;
    const int origBid = xcd_remap(bxx, byy, bzz);
    const int t  = threadIdx.x;
    const int b  = bzz;
    const int m0 = byy * 128;
    const int n0 = bxx * 128;
    const int lane = t & 63;
    const int wid  = t >> 6;
    const int wm = wid >> 1, wn = wid & 1;
    const int lrow = lane & 15, lk = lane >> 4;

    // staging: chunk idx = r*256 + t -> row = idx/8, chunk = idx%8 (16B chunks)
    const int srow   = t >> 3;                       // + r*32
    const int schunk = t & 7;
    const int kphys  = (schunk ^ (srow & 7)) * 8;    // element offset in [0,64)

    const __hip_bfloat16* aBase = A + (size_t)b * sA + (size_t)(m0 + srow) * K + kphys;
    const __hip_bfloat16* bBase = B + (size_t)b * sB + (size_t)(n0 + srow) * K + kphys;
    const int ldsDst = (t & ~63) * 8;                // wave-uniform elem offset; +r*2048

    f32x4 acc[4][4] = {};

    const int nk = K >> 6;
    const int ph = origBid % nk;                     // convoy-breaking phase offset
    for (int kt0 = 0; kt0 < nk; kt0++) {
        int kt = kt0 + ph; if (kt >= nk) kt -= nk;
        __syncthreads();
        const __hip_bfloat16* ak = aBase + (size_t)kt * 64;
        const __hip_bfloat16* bk = bBase + (size_t)kt * 64;
        for (int r = 0; r < 4; r++)
            load_lds16(ak + (size_t)r * 32 * K, &ldsA[ldsDst + r * 2048]);
        for (int r = 0; r < 4; r++)
            load_lds16(bk + (size_t)r * 32 * K, &ldsB[ldsDst + r * 2048]);
        __syncthreads();
        for (int h = 0; h < 2; h++) {
            bf16x8 af[4], bfr[4];
            const int lc = h * 4 + lk;
            for (int i = 0; i < 4; i++) {
                int row = wm * 64 + i * 16 + lrow;
                int pc = lc ^ (row & 7);
                af[i] = *(const bf16x8*)&ldsA[row * 64 + pc * 8];
            }
            for (int i = 0; i < 4; i++) {
                int col = wn * 64 + i * 16 + lrow;
                int pc = lc ^ (col & 7);
                bfr[i] = *(const bf16x8*)&ldsB[col * 64 + pc * 8];
            }
            for (int i = 0; i < 4; i++)
                for (int j = 0; j < 4; j++)
                    acc[i][j] = __builtin_amdgcn_mfma_f32_16x16x32_bf16(
                        af[i], bfr[j], acc[i][j], 0, 0, 0);
        }
    }

    if (vt_out && m0 >= vt_start) {
        // V third of the QKV GEMM: write transposed, vT[p][o-vt_start]
        __hip_bfloat16* vtp = vt_out + (size_t)b * sVT;
        for (int i = 0; i < 4; i++)
            for (int j = 0; j < 4; j++) {
                int row = m0 + wm * 64 + i * 16 + lk * 4;   // o index (row..row+3)
                int col = n0 + wn * 64 + j * 16 + lrow;     // p index
                f32x4 a = acc[i][j];
                ushort4 u;
                u.x = f2bf(a[0] * scale + (bias_row ? bias_row[row + 0] : 0.f));
                u.y = f2bf(a[1] * scale + (bias_row ? bias_row[row + 1] : 0.f));
                u.z = f2bf(a[2] * scale + (bias_row ? bias_row[row + 2] : 0.f));
                u.w = f2bf(a[3] * scale + (bias_row ? bias_row[row + 3] : 0.f));
                *(ushort4*)(vtp + (size_t)col * C_CH + (row - vt_start)) = u;
            }
        return;
    }

    __hip_bfloat16* outB = (__hip_bfloat16*)Cout;
    float* outF = (float*)Cout;
    for (int i = 0; i < 4; i++)
        for (int j = 0; j < 4; j++) {
            int row = m0 + wm * 64 + i * 16 + lk * 4;
            int col = n0 + wn * 64 + j * 16 + lrow;
            f32x4 a = acc[i][j];
            for (int r = 0; r < 4; r++) {
                int rr = row + r;
                float v = a[r] * scale;
                if (bias_row) v += bias_row[rr];
                if (bias_col) v += bias_col[col];
                if (residual) v += residual[(size_t)b * sR + (size_t)rr * ldc + col];
                size_t off = (size_t)b * sC + (size_t)rr * ldc + col;
                if (OUT_F32) outF[off] = v;
                else         outB[off] = __float2bfloat16(v);
            }
        }
}

extern "C" void kernel_launch(void* const* d_in, const int* in_sizes, int n_in,
                              void* d_out, int out_size, void* d_ws, size_t ws_size,
                              hipStream_t stream) {
    const float* x     = (const float*)d_in[0];
    const float* gamma = (const float*)d_in[1];
    const float* beta  = (const float*)d_in[2];
    const float* w_qkv = (const float*)d_in[3];
    const float* b_qkv = (const float*)d_in[4];
    const float* w_out = (const float*)d_in[5];
    const float* b_out = (const float*)d_in[6];

    char* ws = (char*)d_ws;
    size_t off = 0;
    auto alloc = [&](size_t bytes) {
        void* p = ws + off;
        off += (bytes + 255) & ~(size_t)255;
        return p;
    };
    __hip_bfloat16* xnT   = (__hip_bfloat16*)alloc((size_t)BATCH * HW * C_CH * 2);
    __hip_bfloat16* wqkvB = (__hip_bfloat16*)alloc((size_t)3 * C_CH * C_CH * 2);
    __hip_bfloat16* woutB = (__hip_bfloat16*)alloc((size_t)C_CH * C_CH * 2);
    __hip_bfloat16* qk    = (__hip_bfloat16*)alloc((size_t)BATCH * 2 * C_CH * HW * 2);
    __hip_bfloat16* vT    = (__hip_bfloat16*)alloc((size_t)BATCH * HW * C_CH * 2);
    __hip_bfloat16* att   = (__hip_bfloat16*)alloc((size_t)BATCH * C_CH * C_CH * 2);
    __hip_bfloat16* outT  = (__hip_bfloat16*)alloc((size_t)BATCH * HW * C_CH * 2);
    float* stats          = (float*)alloc((size_t)BATCH * NG * 2 * 4);

    // 1) cast weights to bf16
    {
        int n4 = (3 * C_CH * C_CH) / 4;
        cast_bf16_kernel<<<(n4 + 255) / 256, 256, 0, stream>>>(
            (const float4*)w_qkv, (ushort4*)wqkvB, n4);
        int n4b = (C_CH * C_CH) / 4;
        cast_bf16_kernel<<<(n4b + 255) / 256, 256, 0, stream>>>(
            (const float4*)w_out, (ushort4*)woutB, n4b);
    }
    // 2) GroupNorm stats + normalize/transpose
    gn_stats_kernel<<<BATCH * NG, 256, 0, stream>>>(x, stats);
    gn_norm_kernel<<<dim3(HW / 64, BATCH), 256, 0, stream>>>(x, stats, gamma, beta, xnT);

    // 3) QKV GEMM (merged): M=2304, N=1024, K=768.
    //    o < 1536 -> qk[b,o,p]; o >= 1536 -> transposed into vT[b,p,o-1536].
    gemm_nt_kernel<0><<<dim3(HW / 128, 2304 / 128, BATCH), 256, 0, stream>>>(
        wqkvB, 0, xnT, (long)HW * C_CH, qk, (long)2 * C_CH * HW, HW,
        C_CH, 1.0f, b_qkv, nullptr, nullptr, 0,
        vT, (long)HW * C_CH, 2 * C_CH);

    // 4) GEMM2: att[b,i,j] = q.k^T * hw^-0.5  (M=768,N=768,K=1024)
    gemm_nt_kernel<0><<<dim3(C_CH / 128, C_CH / 128, BATCH), 256, 0, stream>>>(
        qk, (long)2 * C_CH * HW, qk + (size_t)C_CH * HW, (long)2 * C_CH * HW,
        att, (long)C_CH * C_CH, C_CH,
        HW, 1.0f / 32.0f, nullptr, nullptr, nullptr, 0,
        nullptr, 0, 0);

    // 5) softmax rows
    softmax_kernel<<<(BATCH * C_CH) / 4, 256, 0, stream>>>(att);

    // 6) GEMM3: out_T[b,p,i] = v_T . att^T  (M=1024,N=768,K=768)
    gemm_nt_kernel<0><<<dim3(C_CH / 128, HW / 128, BATCH), 256, 0, stream>>>(
        vT, (long)HW * C_CH, att, (long)C_CH * C_CH, outT, (long)HW * C_CH, C_CH,
        C_CH, 1.0f, nullptr, nullptr, nullptr, 0,
        nullptr, 0, 0);

    // 7) GEMM4: out[b,o,p] = w_out . out_T^T + b_out + x  (M=768,N=1024,K=768), f32 out
    gemm_nt_kernel<1><<<dim3(HW / 128, C_CH / 128, BATCH), 256, 0, stream>>>(
        woutB, 0, outT, (long)HW * C_CH, (float*)d_out, (long)C_CH * HW, HW,
        C_CH, 1.0f, b_out, nullptr, x, (long)C_CH * HW,
        nullptr, 0, 0);
}

// Round 8
// 228.245 us; speedup vs baseline: 1.0692x; 1.0692x over previous
//
#include <hip/hip_runtime.h>
#include <hip/hip_bf16.h>

#define HW 1024
#define C_CH 768
#define BATCH 16
#define NG 32
#define CPG 24
#define EPS 1e-5f

typedef __attribute__((ext_vector_type(8))) short bf16x8;
typedef __attribute__((ext_vector_type(4))) float f32x4;
typedef unsigned short u16;
typedef unsigned int u32;

typedef const __attribute__((address_space(1))) void* gas_ptr;
typedef __attribute__((address_space(3))) void* las_ptr;

__device__ __forceinline__ void load_lds16(const void* g, void* l) {
    __builtin_amdgcn_global_load_lds((gas_ptr)g, (las_ptr)l, 16, 0, 0);
}

__device__ __forceinline__ u16 f2bf(float f) {
    __hip_bfloat16 h = __float2bfloat16(f);
    return *(u16*)&h;
}
__device__ __forceinline__ float bf2f(u16 u) {
    return __uint_as_float(((u32)u) << 16);
}

// Bijective XCD-chunked swizzle: each XCD gets a CONTIGUOUS chunk of the grid so
// per-XCD L2 working set is a few batches' panels, not all 16 (R6-verified win).
__device__ __forceinline__ void xcd_remap(int& bx, int& by, int& bz) {
    const int nbx = gridDim.x, nby = gridDim.y;
    const int nwg = nbx * nby * gridDim.z;
    int bid = blockIdx.x + nbx * (blockIdx.y + nby * blockIdx.z);
    if ((nwg & 7) == 0) {
        const int q = nwg >> 3;
        bid = (bid & 7) * q + (bid >> 3);
    }
    bx = bid % nbx;
    int t2 = bid / nbx;
    by = t2 % nby;
    bz = t2 / nby;
}

// ---------------- cast f32 -> bf16 (vectorized x4) ----------------
__global__ __launch_bounds__(256) void cast_bf16_kernel(const float4* __restrict__ in,
                                                        ushort4* __restrict__ out, int n4) {
    int i = blockIdx.x * 256 + threadIdx.x;
    if (i >= n4) return;
    float4 v = in[i];
    ushort4 u;
    u.x = f2bf(v.x); u.y = f2bf(v.y); u.z = f2bf(v.z); u.w = f2bf(v.w);
    out[i] = u;
}

// ---------------- GroupNorm stats: one block per (b,g) ----------------
__global__ __launch_bounds__(256) void gn_stats_kernel(const float* __restrict__ x,
                                                       float* __restrict__ stats) {
    int bg = blockIdx.x;                       // b*NG + g
    const float4* p4 = (const float4*)(x + (size_t)bg * (CPG * HW));
    float s = 0.f, s2 = 0.f;
    for (int i = threadIdx.x; i < (CPG * HW) / 4; i += 256) {
        float4 v = p4[i];
        s  += v.x + v.y + v.z + v.w;
        s2 += v.x * v.x + v.y * v.y + v.z * v.z + v.w * v.w;
    }
    int lane = threadIdx.x & 63, wid = threadIdx.x >> 6;
    for (int off = 32; off; off >>= 1) {
        s  += __shfl_xor(s,  off, 64);
        s2 += __shfl_xor(s2, off, 64);
    }
    __shared__ float red[8];
    if (lane == 0) { red[wid * 2] = s; red[wid * 2 + 1] = s2; }
    __syncthreads();
    if (threadIdx.x == 0) {
        s = red[0] + red[2] + red[4] + red[6];
        s2 = red[1] + red[3] + red[5] + red[7];
        float mean = s / (float)(CPG * HW);
        float var  = s2 / (float)(CPG * HW) - mean * mean;
        stats[2 * bg]     = mean;
        stats[2 * bg + 1] = rsqrtf(var + EPS);
    }
}

// ------------- GroupNorm normalize + transpose -> xn_T [B, HW, C] bf16 -------------
__global__ __launch_bounds__(256) void gn_norm_kernel(const float* __restrict__ x,
                                                      const float* __restrict__ stats,
                                                      const float* __restrict__ gamma,
                                                      const float* __restrict__ beta,
                                                      __hip_bfloat16* __restrict__ xnT) {
    __shared__ float lds[64][65];
    int b  = blockIdx.y;
    int p0 = blockIdx.x * 64;
    int t = threadIdx.x;
    int lane = t & 63;
    int grp  = t >> 6;   // 0..3
    for (int cc = 0; cc < C_CH / 64; cc++) {
        int c0 = cc * 64;
        for (int i = 0; i < 16; i++) {
            int c = c0 + grp * 16 + i;
            float2 st = ((const float2*)stats)[b * NG + c / CPG];
            float ga = gamma[c], be = beta[c];
            float v = x[((size_t)b * C_CH + c) * HW + p0 + lane];
            lds[lane][grp * 16 + i] = (v - st.x) * st.y * ga + be;
        }
        __syncthreads();
        for (int i = 0; i < 16; i++) {
            int pp = grp * 16 + i;
            xnT[((size_t)b * HW + p0 + pp) * C_CH + c0 + lane] =
                __float2bfloat16(lds[pp][lane]);
        }
        __syncthreads();
    }
}

// ---------------- row softmax over att [rows][768] bf16, in place ----------------
__global__ __launch_bounds__(256) void softmax_kernel(__hip_bfloat16* __restrict__ att) {
    int row  = blockIdx.x * 4 + (threadIdx.x >> 6);
    int lane = threadIdx.x & 63;
    u16* p = (u16*)(att + (size_t)row * C_CH);
    float v[12];
    float m = -1e30f;
    for (int j = 0; j < 12; j++) {
        v[j] = bf2f(p[j * 64 + lane]);
        m = fmaxf(m, v[j]);
    }
    for (int off = 32; off; off >>= 1) m = fmaxf(m, __shfl_xor(m, off, 64));
    float s = 0.f;
    for (int j = 0; j < 12; j++) { v[j] = __expf(v[j] - m); s += v[j]; }
    for (int off = 32; off; off >>= 1) s += __shfl_xor(s, off, 64);
    float inv = 1.0f / s;
    for (int j = 0; j < 12; j++) p[j * 64 + lane] = f2bf(v[j] * inv);
}

// ---------------- NT GEMM 128x128 (R6-verified, 4 waves) ----------------
template<int OUT_F32>
__global__ __launch_bounds__(256, 2) void gemm_nt_kernel(
    const __hip_bfloat16* __restrict__ A, long sA,
    const __hip_bfloat16* __restrict__ B, long sB,
    void* __restrict__ Cout, long sC, int ldc,
    int K, float scale,
    const float* __restrict__ bias_row,
    const float* __restrict__ bias_col,
    const float* __restrict__ residual, long sR)
{
    __shared__ __hip_bfloat16 ldsA[128 * 64];
    __shared__ __hip_bfloat16 ldsB[128 * 64];
    int bxx, byy, bzz;
    xcd_remap(bxx, byy, bzz);
    const int t  = threadIdx.x;
    const int b  = bzz;
    const int m0 = byy * 128;
    const int n0 = bxx * 128;
    const int lane = t & 63;
    const int wid  = t >> 6;
    const int wm = wid >> 1, wn = wid & 1;
    const int lrow = lane & 15, lk = lane >> 4;

    const int srow   = t >> 3;
    const int schunk = t & 7;
    const int kphys  = (schunk ^ (srow & 7)) * 8;

    const __hip_bfloat16* aBase = A + (size_t)b * sA + (size_t)(m0 + srow) * K + kphys;
    const __hip_bfloat16* bBase = B + (size_t)b * sB + (size_t)(n0 + srow) * K + kphys;
    const int ldsDst = (t & ~63) * 8;

    f32x4 acc[4][4] = {};

    const int nk = K >> 6;
    for (int kt = 0; kt < nk; kt++) {
        __syncthreads();
        const __hip_bfloat16* ak = aBase + (size_t)kt * 64;
        const __hip_bfloat16* bk = bBase + (size_t)kt * 64;
        for (int r = 0; r < 4; r++)
            load_lds16(ak + (size_t)r * 32 * K, &ldsA[ldsDst + r * 2048]);
        for (int r = 0; r < 4; r++)
            load_lds16(bk + (size_t)r * 32 * K, &ldsB[ldsDst + r * 2048]);
        __syncthreads();
        for (int h = 0; h < 2; h++) {
            bf16x8 af[4], bfr[4];
            const int lc = h * 4 + lk;
            for (int i = 0; i < 4; i++) {
                int row = wm * 64 + i * 16 + lrow;
                int pc = lc ^ (row & 7);
                af[i] = *(const bf16x8*)&ldsA[row * 64 + pc * 8];
            }
            for (int i = 0; i < 4; i++) {
                int col = wn * 64 + i * 16 + lrow;
                int pc = lc ^ (col & 7);
                bfr[i] = *(const bf16x8*)&ldsB[col * 64 + pc * 8];
            }
            for (int i = 0; i < 4; i++)
                for (int j = 0; j < 4; j++)
                    acc[i][j] = __builtin_amdgcn_mfma_f32_16x16x32_bf16(
                        af[i], bfr[j], acc[i][j], 0, 0, 0);
        }
    }

    __hip_bfloat16* outB = (__hip_bfloat16*)Cout;
    float* outF = (float*)Cout;
    for (int i = 0; i < 4; i++)
        for (int j = 0; j < 4; j++) {
            int row = m0 + wm * 64 + i * 16 + lk * 4;
            int col = n0 + wn * 64 + j * 16 + lrow;
            f32x4 a = acc[i][j];
            for (int r = 0; r < 4; r++) {
                int rr = row + r;
                float v = a[r] * scale;
                if (bias_row) v += bias_row[rr];
                if (bias_col) v += bias_col[col];
                if (residual) v += residual[(size_t)b * sR + (size_t)rr * ldc + col];
                size_t off = (size_t)b * sC + (size_t)rr * ldc + col;
                if (OUT_F32) outF[off] = v;
                else         outB[off] = __float2bfloat16(v);
            }
        }
}

// ---------------- NT GEMM 256(M)x128(N), 512 thr / 8 waves — for the QKV GEMM ----------------
// Same 2-barrier structure; staging = R3-verified 4+2 pattern; reads = R1-verified swizzle.
// Per K-step: 6 loads/thread (vs 8), barrier events per FLOP halved, ~16 waves/CU.
// Epilogue: rows >= vt_start write transposed into vT[p][o-vt_start] (bf16 quads).
__global__ __launch_bounds__(512, 2) void gemm_nt_qkv(
    const __hip_bfloat16* __restrict__ A,
    const __hip_bfloat16* __restrict__ B, long sB,
    __hip_bfloat16* __restrict__ Cout, long sC, int ldc,
    int K,
    const float* __restrict__ bias_row,
    __hip_bfloat16* __restrict__ vt_out, long sVT, int vt_start)
{
    __shared__ __hip_bfloat16 ldsA[256 * 64];
    __shared__ __hip_bfloat16 ldsB[128 * 64];
    int bxx, byy, bzz;
    xcd_remap(bxx, byy, bzz);
    const int t  = threadIdx.x;
    const int b  = bzz;
    const int m0 = byy * 256;
    const int n0 = bxx * 128;
    const int lane = t & 63;
    const int wid  = t >> 6;
    const int wm = wid >> 1;                         // 0..3 -> 64-row band
    const int wn = wid & 1;                          // 0..1 -> 64-col band
    const int lrow = lane & 15, lk = lane >> 4;

    // staging: chunk c = l*512 + t; row = l*64 + (t>>3); phys chunk = t&7
    const int srow  = t >> 3;                        // 0..63
    const int kphys = ((t & 7) ^ (srow & 7)) * 8;
    const int dstW  = (t & ~63) * 8;                 // wave-uniform elem offset

    const __hip_bfloat16* aBase = A + (size_t)(m0 + srow) * K + kphys;   // weights: no batch
    const __hip_bfloat16* bBase = B + (size_t)b * sB + (size_t)(n0 + srow) * K + kphys;

    f32x4 acc[4][4] = {};

    const int nk = K >> 6;
    for (int kt = 0; kt < nk; kt++) {
        __syncthreads();
        const __hip_bfloat16* ak = aBase + (size_t)kt * 64;
        const __hip_bfloat16* bk = bBase + (size_t)kt * 64;
#pragma unroll
        for (int l = 0; l < 4; l++)
            load_lds16(ak + (size_t)l * 64 * K, &ldsA[dstW + l * 4096]);
#pragma unroll
        for (int l = 0; l < 2; l++)
            load_lds16(bk + (size_t)l * 64 * K, &ldsB[dstW + l * 4096]);
        __syncthreads();
#pragma unroll
        for (int h = 0; h < 2; h++) {
            bf16x8 af[4], bfr[4];
            const int lc = h * 4 + lk;
#pragma unroll
            for (int i = 0; i < 4; i++) {
                int row = wm * 64 + i * 16 + lrow;
                af[i] = *(const bf16x8*)&ldsA[row * 64 + (lc ^ (row & 7)) * 8];
            }
#pragma unroll
            for (int j = 0; j < 4; j++) {
                int col = wn * 64 + j * 16 + lrow;
                bfr[j] = *(const bf16x8*)&ldsB[col * 64 + (lc ^ (col & 7)) * 8];
            }
#pragma unroll
            for (int i = 0; i < 4; i++)
#pragma unroll
                for (int j = 0; j < 4; j++)
                    acc[i][j] = __builtin_amdgcn_mfma_f32_16x16x32_bf16(
                        af[i], bfr[j], acc[i][j], 0, 0, 0);
        }
    }

    if (m0 >= vt_start) {
        // V third: write transposed, vT[p][o - vt_start]
        __hip_bfloat16* vtp = vt_out + (size_t)b * sVT;
#pragma unroll
        for (int i = 0; i < 4; i++)
#pragma unroll
            for (int j = 0; j < 4; j++) {
                int row = m0 + wm * 64 + i * 16 + lk * 4;   // o
                int col = n0 + wn * 64 + j * 16 + lrow;     // p
                f32x4 a = acc[i][j];
                ushort4 u;
                u.x = f2bf(a[0] + bias_row[row + 0]);
                u.y = f2bf(a[1] + bias_row[row + 1]);
                u.z = f2bf(a[2] + bias_row[row + 2]);
                u.w = f2bf(a[3] + bias_row[row + 3]);
                *(ushort4*)(vtp + (size_t)col * C_CH + (row - vt_start)) = u;
            }
        return;
    }

#pragma unroll
    for (int i = 0; i < 4; i++)
#pragma unroll
        for (int j = 0; j < 4; j++) {
            int row = m0 + wm * 64 + i * 16 + lk * 4;
            int col = n0 + wn * 64 + j * 16 + lrow;
            f32x4 a = acc[i][j];
#pragma unroll
            for (int r = 0; r < 4; r++) {
                int rr = row + r;
                Cout[(size_t)b * sC + (size_t)rr * ldc + col] =
                    __float2bfloat16(a[r] + bias_row[rr]);
            }
        }
}

extern "C" void kernel_launch(void* const* d_in, const int* in_sizes, int n_in,
                              void* d_out, int out_size, void* d_ws, size_t ws_size,
                              hipStream_t stream) {
    const float* x     = (const float*)d_in[0];
    const float* gamma = (const float*)d_in[1];
    const float* beta  = (const float*)d_in[2];
    const float* w_qkv = (const float*)d_in[3];
    const float* b_qkv = (const float*)d_in[4];
    const float* w_out = (const float*)d_in[5];
    const float* b_out = (const float*)d_in[6];

    char* ws = (char*)d_ws;
    size_t off = 0;
    auto alloc = [&](size_t bytes) {
        void* p = ws + off;
        off += (bytes + 255) & ~(size_t)255;
        return p;
    };
    __hip_bfloat16* xnT   = (__hip_bfloat16*)alloc((size_t)BATCH * HW * C_CH * 2);
    __hip_bfloat16* wqkvB = (__hip_bfloat16*)alloc((size_t)3 * C_CH * C_CH * 2);
    __hip_bfloat16* woutB = (__hip_bfloat16*)alloc((size_t)C_CH * C_CH * 2);
    __hip_bfloat16* qk    = (__hip_bfloat16*)alloc((size_t)BATCH * 2 * C_CH * HW * 2);
    __hip_bfloat16* vT    = (__hip_bfloat16*)alloc((size_t)BATCH * HW * C_CH * 2);
    __hip_bfloat16* att   = (__hip_bfloat16*)alloc((size_t)BATCH * C_CH * C_CH * 2);
    __hip_bfloat16* outT  = (__hip_bfloat16*)alloc((size_t)BATCH * HW * C_CH * 2);
    float* stats          = (float*)alloc((size_t)BATCH * NG * 2 * 4);

    // 1) cast weights to bf16
    {
        int n4 = (3 * C_CH * C_CH) / 4;
        cast_bf16_kernel<<<(n4 + 255) / 256, 256, 0, stream>>>(
            (const float4*)w_qkv, (ushort4*)wqkvB, n4);
        int n4b = (C_CH * C_CH) / 4;
        cast_bf16_kernel<<<(n4b + 255) / 256, 256, 0, stream>>>(
            (const float4*)w_out, (ushort4*)woutB, n4b);
    }
    // 2) GroupNorm stats + normalize/transpose
    gn_stats_kernel<<<BATCH * NG, 256, 0, stream>>>(x, stats);
    gn_norm_kernel<<<dim3(HW / 64, BATCH), 256, 0, stream>>>(x, stats, gamma, beta, xnT);

    // 3) QKV GEMM (merged, 256x128 tile): M=2304, N=1024, K=768.
    //    o < 1536 -> qk[b,o,p]; o >= 1536 -> transposed into vT[b,p,o-1536].
    gemm_nt_qkv<<<dim3(HW / 128, 2304 / 256, BATCH), 512, 0, stream>>>(
        wqkvB, xnT, (long)HW * C_CH, qk, (long)2 * C_CH * HW, HW,
        C_CH, b_qkv, vT, (long)HW * C_CH, 2 * C_CH);

    // 4) GEMM2: att[b,i,j] = q.k^T * hw^-0.5  (M=768,N=768,K=1024)
    gemm_nt_kernel<0><<<dim3(C_CH / 128, C_CH / 128, BATCH), 256, 0, stream>>>(
        qk, (long)2 * C_CH * HW, qk + (size_t)C_CH * HW, (long)2 * C_CH * HW,
        att, (long)C_CH * C_CH, C_CH,
        HW, 1.0f / 32.0f, nullptr, nullptr, nullptr, 0);

    // 5) softmax rows
    softmax_kernel<<<(BATCH * C_CH) / 4, 256, 0, stream>>>(att);

    // 6) GEMM3: out_T[b,p,i] = v_T . att^T  (M=1024,N=768,K=768)
    gemm_nt_kernel<0><<<dim3(C_CH / 128, HW / 128, BATCH), 256, 0, stream>>>(
        vT, (long)HW * C_CH, att, (long)C_CH * C_CH, outT, (long)HW * C_CH, C_CH,
        C_CH, 1.0f, nullptr, nullptr, nullptr, 0);

    // 7) GEMM4: out[b,o,p] = w_out . out_T^T + b_out + x  (M=768,N=1024,K=768), f32 out
    gemm_nt_kernel<1><<<dim3(HW / 128, C_CH / 128, BATCH), 256, 0, stream>>>(
        woutB, 0, outT, (long)HW * C_CH, (float*)d_out, (long)C_CH * HW, HW,
        C_CH, 1.0f, b_out, nullptr, x, (long)C_CH * HW);
}

// Round 9
// 206.226 us; speedup vs baseline: 1.1833x; 1.1068x over previous
//
#include <hip/hip_runtime.h>
#include <hip/hip_bf16.h>

#define HW 1024
#define C_CH 768
#define BATCH 16
#define NG 32
#define CPG 24
#define EPS 1e-5f

typedef __attribute__((ext_vector_type(8))) short bf16x8;
typedef __attribute__((ext_vector_type(4))) float f32x4;
typedef unsigned short u16;
typedef unsigned int u32;

typedef const __attribute__((address_space(1))) void* gas_ptr;
typedef __attribute__((address_space(3))) void* las_ptr;

__device__ __forceinline__ void load_lds16(const void* g, void* l) {
    __builtin_amdgcn_global_load_lds((gas_ptr)g, (las_ptr)l, 16, 0, 0);
}

__device__ __forceinline__ u16 f2bf(float f) {
    __hip_bfloat16 h = __float2bfloat16(f);
    return *(u16*)&h;
}
__device__ __forceinline__ float bf2f(u16 u) {
    return __uint_as_float(((u32)u) << 16);
}

// Bijective XCD-chunked swizzle: each XCD gets a CONTIGUOUS chunk of the grid so
// per-XCD L2 working set is a few batches' panels, not all 16 (R6-verified win).
__device__ __forceinline__ void xcd_remap(int& bx, int& by, int& bz) {
    const int nbx = gridDim.x, nby = gridDim.y;
    const int nwg = nbx * nby * gridDim.z;
    int bid = blockIdx.x + nbx * (blockIdx.y + nby * blockIdx.z);
    if ((nwg & 7) == 0) {
        const int q = nwg >> 3;
        bid = (bid & 7) * q + (bid >> 3);
    }
    bx = bid % nbx;
    int t2 = bid / nbx;
    by = t2 % nby;
    bz = t2 / nby;
}

// ---------------- cast f32 -> bf16 (vectorized x4) ----------------
__global__ __launch_bounds__(256) void cast_bf16_kernel(const float4* __restrict__ in,
                                                        ushort4* __restrict__ out, int n4) {
    int i = blockIdx.x * 256 + threadIdx.x;
    if (i >= n4) return;
    float4 v = in[i];
    ushort4 u;
    u.x = f2bf(v.x); u.y = f2bf(v.y); u.z = f2bf(v.z); u.w = f2bf(v.w);
    out[i] = u;
}

// ---------- Fused GroupNorm: stats + normalize + transpose in ONE pass ----------
// One block per (b,g). The 24x1024 f32 slab (96 KB) lives in LDS (row pad 1025 to
// break the 1024-stride bank alias). Load coalesced float4 while accumulating
// sum/sumsq; block-reduce; precompute per-channel a=rstd*gamma, b'=beta-mean*a;
// write xnT[b, p, g*24 + c] as ushort4 (24 % 4 == 0 -> quads never cross channels,
// 8B alignment holds). Saves a full 50 MB re-read of x vs the 2-kernel version.
__global__ __launch_bounds__(512) void gn_fused_kernel(const float* __restrict__ x,
                                                       const float* __restrict__ gamma,
                                                       const float* __restrict__ beta,
                                                       __hip_bfloat16* __restrict__ xnT) {
    __shared__ float lds[24 * 1025];
    __shared__ float red[18];
    __shared__ float lga[24], lbe[24];
    const int bg = blockIdx.x;
    const int b = bg >> 5, g = bg & 31;
    const int t = threadIdx.x;
    const float4* src = (const float4*)(x + (size_t)bg * (CPG * HW));

    float s = 0.f, s2 = 0.f;
#pragma unroll 4
    for (int i = 0; i < 12; i++) {
        int fl4 = i * 512 + t;                  // float4 index in [0, 6144)
        float4 v = src[fl4];
        int flat = fl4 * 4;
        int c = flat >> 10, p = flat & 1023;    // float4 never crosses a row
        float* d = &lds[c * 1025 + p];
        d[0] = v.x; d[1] = v.y; d[2] = v.z; d[3] = v.w;
        s  += v.x + v.y + v.z + v.w;
        s2 += v.x * v.x + v.y * v.y + v.z * v.z + v.w * v.w;
    }
    const int lane = t & 63, wid = t >> 6;
    for (int off = 32; off; off >>= 1) {
        s  += __shfl_xor(s,  off, 64);
        s2 += __shfl_xor(s2, off, 64);
    }
    if (lane == 0) { red[wid * 2] = s; red[wid * 2 + 1] = s2; }
    __syncthreads();
    if (t == 0) {
        float ts = 0.f, ts2 = 0.f;
        for (int w = 0; w < 8; w++) { ts += red[w * 2]; ts2 += red[w * 2 + 1]; }
        float mean = ts / (float)(CPG * HW);
        float var  = ts2 / (float)(CPG * HW) - mean * mean;
        red[16] = mean;
        red[17] = rsqrtf(var + EPS);
    }
    __syncthreads();
    const float mean = red[16], rstd = red[17];
    const int cbase = g * CPG;
    if (t < CPG) {
        float a = gamma[cbase + t] * rstd;
        lga[t] = a;
        lbe[t] = beta[cbase + t] - mean * a;
    }
    __syncthreads();

    u16* dst = (u16*)xnT + (size_t)b * HW * C_CH + cbase;
#pragma unroll 4
    for (int i = 0; i < 12; i++) {
        int k = i * 512 + t;                    // ushort4 index in [0, 6144)
        int p = k / 6;
        int c = (k - p * 6) * 4;                // 0,4,8,12,16,20
        ushort4 u;
        u.x = f2bf(lds[(c + 0) * 1025 + p] * lga[c + 0] + lbe[c + 0]);
        u.y = f2bf(lds[(c + 1) * 1025 + p] * lga[c + 1] + lbe[c + 1]);
        u.z = f2bf(lds[(c + 2) * 1025 + p] * lga[c + 2] + lbe[c + 2]);
        u.w = f2bf(lds[(c + 3) * 1025 + p] * lga[c + 3] + lbe[c + 3]);
        *(ushort4*)(dst + (size_t)p * C_CH + c) = u;
    }
}

// ---------------- row softmax over att [rows][768] bf16, in place ----------------
__global__ __launch_bounds__(256) void softmax_kernel(__hip_bfloat16* __restrict__ att) {
    int row  = blockIdx.x * 4 + (threadIdx.x >> 6);
    int lane = threadIdx.x & 63;
    u16* p = (u16*)(att + (size_t)row * C_CH);
    float v[12];
    float m = -1e30f;
    for (int j = 0; j < 12; j++) {
        v[j] = bf2f(p[j * 64 + lane]);
        m = fmaxf(m, v[j]);
    }
    for (int off = 32; off; off >>= 1) m = fmaxf(m, __shfl_xor(m, off, 64));
    float s = 0.f;
    for (int j = 0; j < 12; j++) { v[j] = __expf(v[j] - m); s += v[j]; }
    for (int off = 32; off; off >>= 1) s += __shfl_xor(s, off, 64);
    float inv = 1.0f / s;
    for (int j = 0; j < 12; j++) p[j * 64 + lane] = f2bf(v[j] * inv);
}

// ---------------- NT GEMM 128x128 (R6-verified, 4 waves) ----------------
template<int OUT_F32>
__global__ __launch_bounds__(256, 2) void gemm_nt_kernel(
    const __hip_bfloat16* __restrict__ A, long sA,
    const __hip_bfloat16* __restrict__ B, long sB,
    void* __restrict__ Cout, long sC, int ldc,
    int K, float scale,
    const float* __restrict__ bias_row,
    const float* __restrict__ bias_col,
    const float* __restrict__ residual, long sR)
{
    __shared__ __hip_bfloat16 ldsA[128 * 64];
    __shared__ __hip_bfloat16 ldsB[128 * 64];
    int bxx, byy, bzz;
    xcd_remap(bxx, byy, bzz);
    const int t  = threadIdx.x;
    const int b  = bzz;
    const int m0 = byy * 128;
    const int n0 = bxx * 128;
    const int lane = t & 63;
    const int wid  = t >> 6;
    const int wm = wid >> 1, wn = wid & 1;
    const int lrow = lane & 15, lk = lane >> 4;

    const int srow   = t >> 3;
    const int schunk = t & 7;
    const int kphys  = (schunk ^ (srow & 7)) * 8;

    const __hip_bfloat16* aBase = A + (size_t)b * sA + (size_t)(m0 + srow) * K + kphys;
    const __hip_bfloat16* bBase = B + (size_t)b * sB + (size_t)(n0 + srow) * K + kphys;
    const int ldsDst = (t & ~63) * 8;

    f32x4 acc[4][4] = {};

    const int nk = K >> 6;
    for (int kt = 0; kt < nk; kt++) {
        __syncthreads();
        const __hip_bfloat16* ak = aBase + (size_t)kt * 64;
        const __hip_bfloat16* bk = bBase + (size_t)kt * 64;
        for (int r = 0; r < 4; r++)
            load_lds16(ak + (size_t)r * 32 * K, &ldsA[ldsDst + r * 2048]);
        for (int r = 0; r < 4; r++)
            load_lds16(bk + (size_t)r * 32 * K, &ldsB[ldsDst + r * 2048]);
        __syncthreads();
        for (int h = 0; h < 2; h++) {
            bf16x8 af[4], bfr[4];
            const int lc = h * 4 + lk;
            for (int i = 0; i < 4; i++) {
                int row = wm * 64 + i * 16 + lrow;
                int pc = lc ^ (row & 7);
                af[i] = *(const bf16x8*)&ldsA[row * 64 + pc * 8];
            }
            for (int i = 0; i < 4; i++) {
                int col = wn * 64 + i * 16 + lrow;
                int pc = lc ^ (col & 7);
                bfr[i] = *(const bf16x8*)&ldsB[col * 64 + pc * 8];
            }
            for (int i = 0; i < 4; i++)
                for (int j = 0; j < 4; j++)
                    acc[i][j] = __builtin_amdgcn_mfma_f32_16x16x32_bf16(
                        af[i], bfr[j], acc[i][j], 0, 0, 0);
        }
    }

    __hip_bfloat16* outB = (__hip_bfloat16*)Cout;
    float* outF = (float*)Cout;
    for (int i = 0; i < 4; i++)
        for (int j = 0; j < 4; j++) {
            int row = m0 + wm * 64 + i * 16 + lk * 4;
            int col = n0 + wn * 64 + j * 16 + lrow;
            f32x4 a = acc[i][j];
            for (int r = 0; r < 4; r++) {
                int rr = row + r;
                float v = a[r] * scale;
                if (bias_row) v += bias_row[rr];
                if (bias_col) v += bias_col[col];
                if (residual) v += residual[(size_t)b * sR + (size_t)rr * ldc + col];
                size_t off = (size_t)b * sC + (size_t)rr * ldc + col;
                if (OUT_F32) outF[off] = v;
                else         outB[off] = __float2bfloat16(v);
            }
        }
}

// ---------------- NT GEMM 256(M)x128(N), 512 thr / 8 waves — for the QKV GEMM ----------------
// R8-verified. Per K-step: 6 loads/thread, barrier events per FLOP halved vs 128².
// Epilogue: rows >= vt_start write transposed into vT[p][o-vt_start] (bf16 quads).
__global__ __launch_bounds__(512, 2) void gemm_nt_qkv(
    const __hip_bfloat16* __restrict__ A,
    const __hip_bfloat16* __restrict__ B, long sB,
    __hip_bfloat16* __restrict__ Cout, long sC, int ldc,
    int K,
    const float* __restrict__ bias_row,
    __hip_bfloat16* __restrict__ vt_out, long sVT, int vt_start)
{
    __shared__ __hip_bfloat16 ldsA[256 * 64];
    __shared__ __hip_bfloat16 ldsB[128 * 64];
    int bxx, byy, bzz;
    xcd_remap(bxx, byy, bzz);
    const int t  = threadIdx.x;
    const int b  = bzz;
    const int m0 = byy * 256;
    const int n0 = bxx * 128;
    const int lane = t & 63;
    const int wid  = t >> 6;
    const int wm = wid >> 1;                         // 0..3 -> 64-row band
    const int wn = wid & 1;                          // 0..1 -> 64-col band
    const int lrow = lane & 15, lk = lane >> 4;

    const int srow  = t >> 3;                        // 0..63
    const int kphys = ((t & 7) ^ (srow & 7)) * 8;
    const int dstW  = (t & ~63) * 8;                 // wave-uniform elem offset

    const __hip_bfloat16* aBase = A + (size_t)(m0 + srow) * K + kphys;   // weights: no batch
    const __hip_bfloat16* bBase = B + (size_t)b * sB + (size_t)(n0 + srow) * K + kphys;

    f32x4 acc[4][4] = {};

    const int nk = K >> 6;
    for (int kt = 0; kt < nk; kt++) {
        __syncthreads();
        const __hip_bfloat16* ak = aBase + (size_t)kt * 64;
        const __hip_bfloat16* bk = bBase + (size_t)kt * 64;
#pragma unroll
        for (int l = 0; l < 4; l++)
            load_lds16(ak + (size_t)l * 64 * K, &ldsA[dstW + l * 4096]);
#pragma unroll
        for (int l = 0; l < 2; l++)
            load_lds16(bk + (size_t)l * 64 * K, &ldsB[dstW + l * 4096]);
        __syncthreads();
#pragma unroll
        for (int h = 0; h < 2; h++) {
            bf16x8 af[4], bfr[4];
            const int lc = h * 4 + lk;
#pragma unroll
            for (int i = 0; i < 4; i++) {
                int row = wm * 64 + i * 16 + lrow;
                af[i] = *(const bf16x8*)&ldsA[row * 64 + (lc ^ (row & 7)) * 8];
            }
#pragma unroll
            for (int j = 0; j < 4; j++) {
                int col = wn * 64 + j * 16 + lrow;
                bfr[j] = *(const bf16x8*)&ldsB[col * 64 + (lc ^ (col & 7)) * 8];
            }
#pragma unroll
            for (int i = 0; i < 4; i++)
#pragma unroll
                for (int j = 0; j < 4; j++)
                    acc[i][j] = __builtin_amdgcn_mfma_f32_16x16x32_bf16(
                        af[i], bfr[j], acc[i][j], 0, 0, 0);
        }
    }

    if (m0 >= vt_start) {
        // V third: write transposed, vT[p][o - vt_start]
        __hip_bfloat16* vtp = vt_out + (size_t)b * sVT;
#pragma unroll
        for (int i = 0; i < 4; i++)
#pragma unroll
            for (int j = 0; j < 4; j++) {
                int row = m0 + wm * 64 + i * 16 + lk * 4;   // o
                int col = n0 + wn * 64 + j * 16 + lrow;     // p
                f32x4 a = acc[i][j];
                ushort4 u;
                u.x = f2bf(a[0] + bias_row[row + 0]);
                u.y = f2bf(a[1] + bias_row[row + 1]);
                u.z = f2bf(a[2] + bias_row[row + 2]);
                u.w = f2bf(a[3] + bias_row[row + 3]);
                *(ushort4*)(vtp + (size_t)col * C_CH + (row - vt_start)) = u;
            }
        return;
    }

#pragma unroll
    for (int i = 0; i < 4; i++)
#pragma unroll
        for (int j = 0; j < 4; j++) {
            int row = m0 + wm * 64 + i * 16 + lk * 4;
            int col = n0 + wn * 64 + j * 16 + lrow;
            f32x4 a = acc[i][j];
#pragma unroll
            for (int r = 0; r < 4; r++) {
                int rr = row + r;
                Cout[(size_t)b * sC + (size_t)rr * ldc + col] =
                    __float2bfloat16(a[r] + bias_row[rr]);
            }
        }
}

extern "C" void kernel_launch(void* const* d_in, const int* in_sizes, int n_in,
                              void* d_out, int out_size, void* d_ws, size_t ws_size,
                              hipStream_t stream) {
    const float* x     = (const float*)d_in[0];
    const float* gamma = (const float*)d_in[1];
    const float* beta  = (const float*)d_in[2];
    const float* w_qkv = (const float*)d_in[3];
    const float* b_qkv = (const float*)d_in[4];
    const float* w_out = (const float*)d_in[5];
    const float* b_out = (const float*)d_in[6];

    char* ws = (char*)d_ws;
    size_t off = 0;
    auto alloc = [&](size_t bytes) {
        void* p = ws + off;
        off += (bytes + 255) & ~(size_t)255;
        return p;
    };
    __hip_bfloat16* xnT   = (__hip_bfloat16*)alloc((size_t)BATCH * HW * C_CH * 2);
    __hip_bfloat16* wqkvB = (__hip_bfloat16*)alloc((size_t)3 * C_CH * C_CH * 2);
    __hip_bfloat16* woutB = (__hip_bfloat16*)alloc((size_t)C_CH * C_CH * 2);
    __hip_bfloat16* qk    = (__hip_bfloat16*)alloc((size_t)BATCH * 2 * C_CH * HW * 2);
    __hip_bfloat16* vT    = (__hip_bfloat16*)alloc((size_t)BATCH * HW * C_CH * 2);
    __hip_bfloat16* att   = (__hip_bfloat16*)alloc((size_t)BATCH * C_CH * C_CH * 2);
    __hip_bfloat16* outT  = (__hip_bfloat16*)alloc((size_t)BATCH * HW * C_CH * 2);

    // 1) cast weights to bf16
    {
        int n4 = (3 * C_CH * C_CH) / 4;
        cast_bf16_kernel<<<(n4 + 255) / 256, 256, 0, stream>>>(
            (const float4*)w_qkv, (ushort4*)wqkvB, n4);
        int n4b = (C_CH * C_CH) / 4;
        cast_bf16_kernel<<<(n4b + 255) / 256, 256, 0, stream>>>(
            (const float4*)w_out, (ushort4*)woutB, n4b);
    }
    // 2) Fused GroupNorm (stats + normalize + transpose, single pass over x)
    gn_fused_kernel<<<BATCH * NG, 512, 0, stream>>>(x, gamma, beta, xnT);

    // 3) QKV GEMM (merged, 256x128 tile): M=2304, N=1024, K=768.
    //    o < 1536 -> qk[b,o,p]; o >= 1536 -> transposed into vT[b,p,o-1536].
    gemm_nt_qkv<<<dim3(HW / 128, 2304 / 256, BATCH), 512, 0, stream>>>(
        wqkvB, xnT, (long)HW * C_CH, qk, (long)2 * C_CH * HW, HW,
        C_CH, b_qkv, vT, (long)HW * C_CH, 2 * C_CH);

    // 4) GEMM2: att[b,i,j] = q.k^T * hw^-0.5  (M=768,N=768,K=1024)
    gemm_nt_kernel<0><<<dim3(C_CH / 128, C_CH / 128, BATCH), 256, 0, stream>>>(
        qk, (long)2 * C_CH * HW, qk + (size_t)C_CH * HW, (long)2 * C_CH * HW,
        att, (long)C_CH * C_CH, C_CH,
        HW, 1.0f / 32.0f, nullptr, nullptr, nullptr, 0);

    // 5) softmax rows
    softmax_kernel<<<(BATCH * C_CH) / 4, 256, 0, stream>>>(att);

    // 6) GEMM3: out_T[b,p,i] = v_T . att^T  (M=1024,N=768,K=768)
    gemm_nt_kernel<0><<<dim3(C_CH / 128, HW / 128, BATCH), 256, 0, stream>>>(
        vT, (long)HW * C_CH, att, (long)C_CH * C_CH, outT, (long)HW * C_CH, C_CH,
        C_CH, 1.0f, nullptr, nullptr, nullptr, 0);

    // 7) GEMM4: out[b,o,p] = w_out . out_T^T + b_out + x  (M=768,N=1024,K=768), f32 out
    gemm_nt_kernel<1><<<dim3(HW / 128, C_CH / 128, BATCH), 256, 0, stream>>>(
        woutB, 0, outT, (long)HW * C_CH, (float*)d_out, (long)C_CH * HW, HW,
        C_CH, 1.0f, b_out, nullptr, x, (long)C_CH * HW);
}

// Round 11
// 191.447 us; speedup vs baseline: 1.2747x; 1.0772x over previous
//
#include <hip/hip_runtime.h>
#include <hip/hip_bf16.h>

#define HW 1024
#define C_CH 768
#define BATCH 16
#define NG 32
#define CPG 24
#define EPS 1e-5f

typedef __attribute__((ext_vector_type(8))) short bf16x8;
typedef __attribute__((ext_vector_type(4))) float f32x4;
typedef unsigned short u16;
typedef unsigned int u32;

typedef const __attribute__((address_space(1))) void* gas_ptr;
typedef __attribute__((address_space(3))) void* las_ptr;

__device__ __forceinline__ void load_lds16(const void* g, void* l) {
    __builtin_amdgcn_global_load_lds((gas_ptr)g, (las_ptr)l, 16, 0, 0);
}

__device__ __forceinline__ u16 f2bf(float f) {
    __hip_bfloat16 h = __float2bfloat16(f);
    return *(u16*)&h;
}
__device__ __forceinline__ float bf2f(u16 u) {
    return __uint_as_float(((u32)u) << 16);
}

// Bijective XCD-chunked swizzle (R6-verified win).
__device__ __forceinline__ void xcd_remap(int& bx, int& by, int& bz) {
    const int nbx = gridDim.x, nby = gridDim.y;
    const int nwg = nbx * nby * gridDim.z;
    int bid = blockIdx.x + nbx * (blockIdx.y + nby * blockIdx.z);
    if ((nwg & 7) == 0) {
        const int q = nwg >> 3;
        bid = (bid & 7) * q + (bid >> 3);
    }
    bx = bid % nbx;
    int t2 = bid / nbx;
    by = t2 % nby;
    bz = t2 / nby;
}

// ---------------- cast f32 -> bf16 (vectorized x4) ----------------
__global__ __launch_bounds__(256) void cast_bf16_kernel(const float4* __restrict__ in,
                                                        ushort4* __restrict__ out, int n4) {
    int i = blockIdx.x * 256 + threadIdx.x;
    if (i >= n4) return;
    float4 v = in[i];
    ushort4 u;
    u.x = f2bf(v.x); u.y = f2bf(v.y); u.z = f2bf(v.z); u.w = f2bf(v.w);
    out[i] = u;
}

// ---------- Fused GroupNorm: stats + normalize + transpose in ONE pass (R9-verified) ----------
__global__ __launch_bounds__(512) void gn_fused_kernel(const float* __restrict__ x,
                                                       const float* __restrict__ gamma,
                                                       const float* __restrict__ beta,
                                                       __hip_bfloat16* __restrict__ xnT) {
    __shared__ float lds[24 * 1025];
    __shared__ float red[18];
    __shared__ float lga[24], lbe[24];
    const int bg = blockIdx.x;
    const int b = bg >> 5, g = bg & 31;
    const int t = threadIdx.x;
    const float4* src = (const float4*)(x + (size_t)bg * (CPG * HW));

    float s = 0.f, s2 = 0.f;
#pragma unroll 4
    for (int i = 0; i < 12; i++) {
        int fl4 = i * 512 + t;
        float4 v = src[fl4];
        int flat = fl4 * 4;
        int c = flat >> 10, p = flat & 1023;
        float* d = &lds[c * 1025 + p];
        d[0] = v.x; d[1] = v.y; d[2] = v.z; d[3] = v.w;
        s  += v.x + v.y + v.z + v.w;
        s2 += v.x * v.x + v.y * v.y + v.z * v.z + v.w * v.w;
    }
    const int lane = t & 63, wid = t >> 6;
    for (int off = 32; off; off >>= 1) {
        s  += __shfl_xor(s,  off, 64);
        s2 += __shfl_xor(s2, off, 64);
    }
    if (lane == 0) { red[wid * 2] = s; red[wid * 2 + 1] = s2; }
    __syncthreads();
    if (t == 0) {
        float ts = 0.f, ts2 = 0.f;
        for (int w = 0; w < 8; w++) { ts += red[w * 2]; ts2 += red[w * 2 + 1]; }
        float mean = ts / (float)(CPG * HW);
        float var  = ts2 / (float)(CPG * HW) - mean * mean;
        red[16] = mean;
        red[17] = rsqrtf(var + EPS);
    }
    __syncthreads();
    const float mean = red[16], rstd = red[17];
    const int cbase = g * CPG;
    if (t < CPG) {
        float a = gamma[cbase + t] * rstd;
        lga[t] = a;
        lbe[t] = beta[cbase + t] - mean * a;
    }
    __syncthreads();

    u16* dst = (u16*)xnT + (size_t)b * HW * C_CH + cbase;
#pragma unroll 4
    for (int i = 0; i < 12; i++) {
        int k = i * 512 + t;
        int p = k / 6;
        int c = (k - p * 6) * 4;
        ushort4 u;
        u.x = f2bf(lds[(c + 0) * 1025 + p] * lga[c + 0] + lbe[c + 0]);
        u.y = f2bf(lds[(c + 1) * 1025 + p] * lga[c + 1] + lbe[c + 1]);
        u.z = f2bf(lds[(c + 2) * 1025 + p] * lga[c + 2] + lbe[c + 2]);
        u.w = f2bf(lds[(c + 3) * 1025 + p] * lga[c + 3] + lbe[c + 3]);
        *(ushort4*)(dst + (size_t)p * C_CH + c) = u;
    }
}

// ------------- row softmax over att [rows][768] bf16, in place (R8/R9-proven u16 version) -------------
__global__ __launch_bounds__(256) void softmax_kernel(__hip_bfloat16* __restrict__ att) {
    int row  = blockIdx.x * 4 + (threadIdx.x >> 6);
    int lane = threadIdx.x & 63;
    u16* p = (u16*)(att + (size_t)row * C_CH);
    float v[12];
    float m = -1e30f;
    for (int j = 0; j < 12; j++) {
        v[j] = bf2f(p[j * 64 + lane]);
        m = fmaxf(m, v[j]);
    }
    for (int off = 32; off; off >>= 1) m = fmaxf(m, __shfl_xor(m, off, 64));
    float s = 0.f;
    for (int j = 0; j < 12; j++) { v[j] = __expf(v[j] - m); s += v[j]; }
    for (int off = 32; off; off >>= 1) s += __shfl_xor(s, off, 64);
    float inv = 1.0f / s;
    for (int j = 0; j < 12; j++) p[j * 64 + lane] = f2bf(v[j] * inv);
}

// ---------------- NT GEMM 128x128 (R6-verified, 4 waves) — used for GEMM2 only ----------------
template<int OUT_F32>
__global__ __launch_bounds__(256, 2) void gemm_nt_kernel(
    const __hip_bfloat16* __restrict__ A, long sA,
    const __hip_bfloat16* __restrict__ B, long sB,
    void* __restrict__ Cout, long sC, int ldc,
    int K, float scale,
    const float* __restrict__ bias_row,
    const float* __restrict__ bias_col,
    const float* __restrict__ residual, long sR)
{
    __shared__ __hip_bfloat16 ldsA[128 * 64];
    __shared__ __hip_bfloat16 ldsB[128 * 64];
    int bxx, byy, bzz;
    xcd_remap(bxx, byy, bzz);
    const int t  = threadIdx.x;
    const int b  = bzz;
    const int m0 = byy * 128;
    const int n0 = bxx * 128;
    const int lane = t & 63;
    const int wid  = t >> 6;
    const int wm = wid >> 1, wn = wid & 1;
    const int lrow = lane & 15, lk = lane >> 4;

    const int srow   = t >> 3;
    const int schunk = t & 7;
    const int kphys  = (schunk ^ (srow & 7)) * 8;

    const __hip_bfloat16* aBase = A + (size_t)b * sA + (size_t)(m0 + srow) * K + kphys;
    const __hip_bfloat16* bBase = B + (size_t)b * sB + (size_t)(n0 + srow) * K + kphys;
    const int ldsDst = (t & ~63) * 8;

    f32x4 acc[4][4] = {};

    const int nk = K >> 6;
    for (int kt = 0; kt < nk; kt++) {
        __syncthreads();
        const __hip_bfloat16* ak = aBase + (size_t)kt * 64;
        const __hip_bfloat16* bk = bBase + (size_t)kt * 64;
        for (int r = 0; r < 4; r++)
            load_lds16(ak + (size_t)r * 32 * K, &ldsA[ldsDst + r * 2048]);
        for (int r = 0; r < 4; r++)
            load_lds16(bk + (size_t)r * 32 * K, &ldsB[ldsDst + r * 2048]);
        __syncthreads();
        for (int h = 0; h < 2; h++) {
            bf16x8 af[4], bfr[4];
            const int lc = h * 4 + lk;
            for (int i = 0; i < 4; i++) {
                int row = wm * 64 + i * 16 + lrow;
                int pc = lc ^ (row & 7);
                af[i] = *(const bf16x8*)&ldsA[row * 64 + pc * 8];
            }
            for (int i = 0; i < 4; i++) {
                int col = wn * 64 + i * 16 + lrow;
                int pc = lc ^ (col & 7);
                bfr[i] = *(const bf16x8*)&ldsB[col * 64 + pc * 8];
            }
            for (int i = 0; i < 4; i++)
                for (int j = 0; j < 4; j++)
                    acc[i][j] = __builtin_amdgcn_mfma_f32_16x16x32_bf16(
                        af[i], bfr[j], acc[i][j], 0, 0, 0);
        }
    }

    __hip_bfloat16* outB = (__hip_bfloat16*)Cout;
    float* outF = (float*)Cout;
    for (int i = 0; i < 4; i++)
        for (int j = 0; j < 4; j++) {
            int row = m0 + wm * 64 + i * 16 + lk * 4;
            int col = n0 + wn * 64 + j * 16 + lrow;
            f32x4 a = acc[i][j];
            for (int r = 0; r < 4; r++) {
                int rr = row + r;
                float v = a[r] * scale;
                if (bias_row) v += bias_row[rr];
                if (bias_col) v += bias_col[col];
                if (residual) v += residual[(size_t)b * sR + (size_t)rr * ldc + col];
                size_t off = (size_t)b * sC + (size_t)rr * ldc + col;
                if (OUT_F32) outF[off] = v;
                else         outB[off] = __float2bfloat16(v);
            }
        }
}

// ---------------- NT GEMM 256(M)x128(N), 512 thr / 8 waves — QKV (R8/R9-verified, verbatim) ----------------
__global__ __launch_bounds__(512, 2) void gemm_nt_qkv(
    const __hip_bfloat16* __restrict__ A,
    const __hip_bfloat16* __restrict__ B, long sB,
    __hip_bfloat16* __restrict__ Cout, long sC, int ldc,
    int K,
    const float* __restrict__ bias_row,
    __hip_bfloat16* __restrict__ vt_out, long sVT, int vt_start)
{
    __shared__ __hip_bfloat16 ldsA[256 * 64];
    __shared__ __hip_bfloat16 ldsB[128 * 64];
    int bxx, byy, bzz;
    xcd_remap(bxx, byy, bzz);
    const int t  = threadIdx.x;
    const int b  = bzz;
    const int m0 = byy * 256;
    const int n0 = bxx * 128;
    const int lane = t & 63;
    const int wid  = t >> 6;
    const int wm = wid >> 1;
    const int wn = wid & 1;
    const int lrow = lane & 15, lk = lane >> 4;

    const int srow  = t >> 3;
    const int kphys = ((t & 7) ^ (srow & 7)) * 8;
    const int dstW  = (t & ~63) * 8;

    const __hip_bfloat16* aBase = A + (size_t)(m0 + srow) * K + kphys;
    const __hip_bfloat16* bBase = B + (size_t)b * sB + (size_t)(n0 + srow) * K + kphys;

    f32x4 acc[4][4] = {};

    const int nk = K >> 6;
    for (int kt = 0; kt < nk; kt++) {
        __syncthreads();
        const __hip_bfloat16* ak = aBase + (size_t)kt * 64;
        const __hip_bfloat16* bk = bBase + (size_t)kt * 64;
#pragma unroll
        for (int l = 0; l < 4; l++)
            load_lds16(ak + (size_t)l * 64 * K, &ldsA[dstW + l * 4096]);
#pragma unroll
        for (int l = 0; l < 2; l++)
            load_lds16(bk + (size_t)l * 64 * K, &ldsB[dstW + l * 4096]);
        __syncthreads();
#pragma unroll
        for (int h = 0; h < 2; h++) {
            bf16x8 af[4], bfr[4];
            const int lc = h * 4 + lk;
#pragma unroll
            for (int i = 0; i < 4; i++) {
                int row = wm * 64 + i * 16 + lrow;
                af[i] = *(const bf16x8*)&ldsA[row * 64 + (lc ^ (row & 7)) * 8];
            }
#pragma unroll
            for (int j = 0; j < 4; j++) {
                int col = wn * 64 + j * 16 + lrow;
                bfr[j] = *(const bf16x8*)&ldsB[col * 64 + (lc ^ (col & 7)) * 8];
            }
#pragma unroll
            for (int i = 0; i < 4; i++)
#pragma unroll
                for (int j = 0; j < 4; j++)
                    acc[i][j] = __builtin_amdgcn_mfma_f32_16x16x32_bf16(
                        af[i], bfr[j], acc[i][j], 0, 0, 0);
        }
    }

    if (m0 >= vt_start) {
        __hip_bfloat16* vtp = vt_out + (size_t)b * sVT;
#pragma unroll
        for (int i = 0; i < 4; i++)
#pragma unroll
            for (int j = 0; j < 4; j++) {
                int row = m0 + wm * 64 + i * 16 + lk * 4;   // o
                int col = n0 + wn * 64 + j * 16 + lrow;     // p
                f32x4 a = acc[i][j];
                ushort4 u;
                u.x = f2bf(a[0] + bias_row[row + 0]);
                u.y = f2bf(a[1] + bias_row[row + 1]);
                u.z = f2bf(a[2] + bias_row[row + 2]);
                u.w = f2bf(a[3] + bias_row[row + 3]);
                *(ushort4*)(vtp + (size_t)col * C_CH + (row - vt_start)) = u;
            }
        return;
    }

#pragma unroll
    for (int i = 0; i < 4; i++)
#pragma unroll
        for (int j = 0; j < 4; j++) {
            int row = m0 + wm * 64 + i * 16 + lk * 4;
            int col = n0 + wn * 64 + j * 16 + lrow;
            f32x4 a = acc[i][j];
#pragma unroll
            for (int r = 0; r < 4; r++) {
                int rr = row + r;
                Cout[(size_t)b * sC + (size_t)rr * ldc + col] =
                    __float2bfloat16(a[r] + bias_row[rr]);
            }
        }
}

// ---------------- GEMM3 (PV): outT[b,p,i] = sum_j vT[b,p,j] * att[b,i,j] ----------------
// Hand-specialized copy of the proven gemm_nt_qkv inner loop; hardcoded strides.
// M=1024 (p, 256-tiles), N=768 (i, 128-tiles), K=768. Grid (6, 4, 16).
__global__ __launch_bounds__(512, 2) void gemm3_pv(
    const __hip_bfloat16* __restrict__ vT,
    const __hip_bfloat16* __restrict__ att,
    __hip_bfloat16* __restrict__ outT)
{
    __shared__ __hip_bfloat16 ldsA[256 * 64];
    __shared__ __hip_bfloat16 ldsB[128 * 64];
    int bxx, byy, bzz;
    xcd_remap(bxx, byy, bzz);
    const int t  = threadIdx.x;
    const int b  = bzz;
    const int m0 = byy * 256;          // p tile
    const int n0 = bxx * 128;          // i tile
    const int lane = t & 63;
    const int wid  = t >> 6;
    const int wm = wid >> 1;
    const int wn = wid & 1;
    const int lrow = lane & 15, lk = lane >> 4;

    const int srow  = t >> 3;
    const int kphys = ((t & 7) ^ (srow & 7)) * 8;
    const int dstW  = (t & ~63) * 8;

    const __hip_bfloat16* aBase = vT  + (size_t)b * (HW * C_CH)   + (size_t)(m0 + srow) * C_CH + kphys;
    const __hip_bfloat16* bBase = att + (size_t)b * (C_CH * C_CH) + (size_t)(n0 + srow) * C_CH + kphys;

    f32x4 acc[4][4] = {};

    for (int kt = 0; kt < C_CH / 64; kt++) {
        __syncthreads();
        const __hip_bfloat16* ak = aBase + (size_t)kt * 64;
        const __hip_bfloat16* bk = bBase + (size_t)kt * 64;
#pragma unroll
        for (int l = 0; l < 4; l++)
            load_lds16(ak + (size_t)l * 64 * C_CH, &ldsA[dstW + l * 4096]);
#pragma unroll
        for (int l = 0; l < 2; l++)
            load_lds16(bk + (size_t)l * 64 * C_CH, &ldsB[dstW + l * 4096]);
        __syncthreads();
#pragma unroll
        for (int h = 0; h < 2; h++) {
            bf16x8 af[4], bfr[4];
            const int lc = h * 4 + lk;
#pragma unroll
            for (int i = 0; i < 4; i++) {
                int row = wm * 64 + i * 16 + lrow;
                af[i] = *(const bf16x8*)&ldsA[row * 64 + (lc ^ (row & 7)) * 8];
            }
#pragma unroll
            for (int j = 0; j < 4; j++) {
                int col = wn * 64 + j * 16 + lrow;
                bfr[j] = *(const bf16x8*)&ldsB[col * 64 + (lc ^ (col & 7)) * 8];
            }
#pragma unroll
            for (int i = 0; i < 4; i++)
#pragma unroll
                for (int j = 0; j < 4; j++)
                    acc[i][j] = __builtin_amdgcn_mfma_f32_16x16x32_bf16(
                        af[i], bfr[j], acc[i][j], 0, 0, 0);
        }
    }

#pragma unroll
    for (int i = 0; i < 4; i++)
#pragma unroll
        for (int j = 0; j < 4; j++) {
            int row = m0 + wm * 64 + i * 16 + lk * 4;   // p
            int col = n0 + wn * 64 + j * 16 + lrow;     // i
            f32x4 a = acc[i][j];
#pragma unroll
            for (int r = 0; r < 4; r++)
                outT[(size_t)b * (HW * C_CH) + (size_t)(row + r) * C_CH + col] =
                    __float2bfloat16(a[r]);
        }
}

// ------------- GEMM4 (proj): out[b,o,p] = sum_i w_out[o,i]*outT[b,p,i] + b_out[o] + x[b,o,p] -------------
// Hand-specialized; hardcoded strides. M=768 (o, 256-tiles), N=1024 (p, 128-tiles), K=768.
// Grid (8, 3, 16). f32 output.
__global__ __launch_bounds__(512, 2) void gemm4_proj(
    const __hip_bfloat16* __restrict__ wo,
    const __hip_bfloat16* __restrict__ outT,
    const float* __restrict__ b_out,
    const float* __restrict__ x,
    float* __restrict__ out)
{
    __shared__ __hip_bfloat16 ldsA[256 * 64];
    __shared__ __hip_bfloat16 ldsB[128 * 64];
    int bxx, byy, bzz;
    xcd_remap(bxx, byy, bzz);
    const int t  = threadIdx.x;
    const int b  = bzz;
    const int m0 = byy * 256;          // o tile
    const int n0 = bxx * 128;          // p tile
    const int lane = t & 63;
    const int wid  = t >> 6;
    const int wm = wid >> 1;
    const int wn = wid & 1;
    const int lrow = lane & 15, lk = lane >> 4;

    const int srow  = t >> 3;
    const int kphys = ((t & 7) ^ (srow & 7)) * 8;
    const int dstW  = (t & ~63) * 8;

    const __hip_bfloat16* aBase = wo   + (size_t)(m0 + srow) * C_CH + kphys;
    const __hip_bfloat16* bBase = outT + (size_t)b * (HW * C_CH) + (size_t)(n0 + srow) * C_CH + kphys;

    f32x4 acc[4][4] = {};

    for (int kt = 0; kt < C_CH / 64; kt++) {
        __syncthreads();
        const __hip_bfloat16* ak = aBase + (size_t)kt * 64;
        const __hip_bfloat16* bk = bBase + (size_t)kt * 64;
#pragma unroll
        for (int l = 0; l < 4; l++)
            load_lds16(ak + (size_t)l * 64 * C_CH, &ldsA[dstW + l * 4096]);
#pragma unroll
        for (int l = 0; l < 2; l++)
            load_lds16(bk + (size_t)l * 64 * C_CH, &ldsB[dstW + l * 4096]);
        __syncthreads();
#pragma unroll
        for (int h = 0; h < 2; h++) {
            bf16x8 af[4], bfr[4];
            const int lc = h * 4 + lk;
#pragma unroll
            for (int i = 0; i < 4; i++) {
                int row = wm * 64 + i * 16 + lrow;
                af[i] = *(const bf16x8*)&ldsA[row * 64 + (lc ^ (row & 7)) * 8];
            }
#pragma unroll
            for (int j = 0; j < 4; j++) {
                int col = wn * 64 + j * 16 + lrow;
                bfr[j] = *(const bf16x8*)&ldsB[col * 64 + (lc ^ (col & 7)) * 8];
            }
#pragma unroll
            for (int i = 0; i < 4; i++)
#pragma unroll
                for (int j = 0; j < 4; j++)
                    acc[i][j] = __builtin_amdgcn_mfma_f32_16x16x32_bf16(
                        af[i], bfr[j], acc[i][j], 0, 0, 0);
        }
    }

#pragma unroll
    for (int i = 0; i < 4; i++)
#pragma unroll
        for (int j = 0; j < 4; j++) {
            int row = m0 + wm * 64 + i * 16 + lk * 4;   // o
            int col = n0 + wn * 64 + j * 16 + lrow;     // p
            f32x4 a = acc[i][j];
#pragma unroll
            for (int r = 0; r < 4; r++) {
                size_t off = (size_t)b * (C_CH * HW) + (size_t)(row + r) * HW + col;
                out[off] = a[r] + b_out[row + r] + x[off];
            }
        }
}

extern "C" void kernel_launch(void* const* d_in, const int* in_sizes, int n_in,
                              void* d_out, int out_size, void* d_ws, size_t ws_size,
                              hipStream_t stream) {
    const float* x     = (const float*)d_in[0];
    const float* gamma = (const float*)d_in[1];
    const float* beta  = (const float*)d_in[2];
    const float* w_qkv = (const float*)d_in[3];
    const float* b_qkv = (const float*)d_in[4];
    const float* w_out = (const float*)d_in[5];
    const float* b_out = (const float*)d_in[6];

    char* ws = (char*)d_ws;
    size_t off = 0;
    auto alloc = [&](size_t bytes) {
        void* p = ws + off;
        off += (bytes + 255) & ~(size_t)255;
        return p;
    };
    __hip_bfloat16* xnT   = (__hip_bfloat16*)alloc((size_t)BATCH * HW * C_CH * 2);
    __hip_bfloat16* wqkvB = (__hip_bfloat16*)alloc((size_t)3 * C_CH * C_CH * 2);
    __hip_bfloat16* woutB = (__hip_bfloat16*)alloc((size_t)C_CH * C_CH * 2);
    __hip_bfloat16* qk    = (__hip_bfloat16*)alloc((size_t)BATCH * 2 * C_CH * HW * 2);
    __hip_bfloat16* vT    = (__hip_bfloat16*)alloc((size_t)BATCH * HW * C_CH * 2);
    __hip_bfloat16* att   = (__hip_bfloat16*)alloc((size_t)BATCH * C_CH * C_CH * 2);
    __hip_bfloat16* outT  = (__hip_bfloat16*)alloc((size_t)BATCH * HW * C_CH * 2);

    // 1) cast weights to bf16
    {
        int n4 = (3 * C_CH * C_CH) / 4;
        cast_bf16_kernel<<<(n4 + 255) / 256, 256, 0, stream>>>(
            (const float4*)w_qkv, (ushort4*)wqkvB, n4);
        int n4b = (C_CH * C_CH) / 4;
        cast_bf16_kernel<<<(n4b + 255) / 256, 256, 0, stream>>>(
            (const float4*)w_out, (ushort4*)woutB, n4b);
    }
    // 2) Fused GroupNorm (stats + normalize + transpose, single pass over x)
    gn_fused_kernel<<<BATCH * NG, 512, 0, stream>>>(x, gamma, beta, xnT);

    // 3) QKV GEMM (merged, 256x128): M=2304, N=1024, K=768.
    //    o < 1536 -> qk[b,o,p]; o >= 1536 -> transposed into vT[b,p,o-1536].
    gemm_nt_qkv<<<dim3(HW / 128, 2304 / 256, BATCH), 512, 0, stream>>>(
        wqkvB, xnT, (long)HW * C_CH, qk, (long)2 * C_CH * HW, HW,
        C_CH, b_qkv, vT, (long)HW * C_CH, 2 * C_CH);

    // 4) GEMM2: att[b,i,j] = q.k^T * hw^-0.5  (M=768,N=768,K=1024), 128² kernel
    gemm_nt_kernel<0><<<dim3(C_CH / 128, C_CH / 128, BATCH), 256, 0, stream>>>(
        qk, (long)2 * C_CH * HW, qk + (size_t)C_CH * HW, (long)2 * C_CH * HW,
        att, (long)C_CH * C_CH, C_CH,
        HW, 1.0f / 32.0f, nullptr, nullptr, nullptr, 0);

    // 5) softmax rows
    softmax_kernel<<<(BATCH * C_CH) / 4, 256, 0, stream>>>(att);

    // 6) GEMM3: outT[b,p,i] = vT . att^T  (M=1024,N=768,K=768), specialized 256x128
    gemm3_pv<<<dim3(C_CH / 128, HW / 256, BATCH), 512, 0, stream>>>(vT, att, outT);

    // 7) GEMM4: out[b,o,p] = w_out . outT^T + b_out + x  (M=768,N=1024,K=768),
    //    specialized 256x128, f32 out + residual
    gemm4_proj<<<dim3(HW / 128, C_CH / 256, BATCH), 512, 0, stream>>>(
        woutB, outT, b_out, x, (float*)d_out);
}